// Round 1
// baseline (192.626 us; speedup 1.0000x reference)
//
#include <hip/hip_runtime.h>

// Pure embedding gather: out[i, :] = table[idx[i], :]
// N_IDX = 1,048,576 rows, D = 128 fp32 (512 B per row).
//
// Layout: 32 lanes per row, one float4 (16 B) per lane -> each half-wave
// moves one contiguous 512 B row. 256-thread block = 8 rows.

__global__ __launch_bounds__(256) void embed_gather_kernel(
    const int* __restrict__ idx,
    const float4* __restrict__ table,   // [N_EMB * 32] float4
    float4* __restrict__ out,           // [N_IDX * 32] float4
    int n_idx) {
  int t = blockIdx.x * 256 + threadIdx.x;
  int row = t >> 5;        // which output row
  int col = t & 31;        // which float4 within the row (32 * 16B = 512B)
  if (row < n_idx) {
    int src = idx[row];    // 32 lanes read the same index -> L1 broadcast
    out[(size_t)row * 32 + col] = table[(size_t)src * 32 + col];
  }
}

extern "C" void kernel_launch(void* const* d_in, const int* in_sizes, int n_in,
                              void* d_out, int out_size, void* d_ws, size_t ws_size,
                              hipStream_t stream) {
  const int*    idx   = (const int*)d_in[0];      // "input": int indices [N_IDX]
  const float4* table = (const float4*)d_in[1];   // "table": fp32 [N_EMB, 128]
  float4*       out   = (float4*)d_out;           // fp32 [N_IDX, 128]

  int n_idx = in_sizes[0];
  // 32 threads per row -> total threads = n_idx * 32
  int total_threads = n_idx * 32;
  int block = 256;
  int grid = (total_threads + block - 1) / block;

  embed_gather_kernel<<<grid, block, 0, stream>>>(idx, table, out, n_idx);
}

// Round 3
// 171.476 us; speedup vs baseline: 1.1233x; 1.1233x over previous
//
#include <hip/hip_runtime.h>

// Embedding gather: out[i, :] = table[idx[i], :]
// N_IDX = 1,048,576 rows, D = 128 fp32 (512 B per row).
//
// 32 lanes per row, one 16B vector per lane -> each half-wave moves one
// contiguous 512 B row. Output stream has zero reuse -> non-temporal stores
// keep it out of L2/L3 so the table's ~333 MB unique footprint (1.6x reuse)
// stays cached.
//
// Use a clang-native ext_vector_type: __builtin_nontemporal_store rejects
// HIP_vector_type<float,4> (R2 compile error).

typedef float f32x4 __attribute__((ext_vector_type(4)));

__global__ __launch_bounds__(256) void embed_gather_kernel(
    const int* __restrict__ idx,
    const f32x4* __restrict__ table,    // [N_EMB * 32] 16B vectors
    f32x4* __restrict__ out,            // [N_IDX * 32]
    int n_idx) {
  int t = blockIdx.x * 256 + threadIdx.x;
  int row = t >> 5;        // which output row
  int col = t & 31;        // which 16B chunk within the row (32 * 16B = 512B)
  if (row < n_idx) {
    int src = idx[row];    // lanes 0-31 / 32-63 broadcast two addresses per wave
    f32x4 v = table[(size_t)src * 32 + col];                       // cached read
    __builtin_nontemporal_store(v, &out[(size_t)row * 32 + col]);  // nt write
  }
}

extern "C" void kernel_launch(void* const* d_in, const int* in_sizes, int n_in,
                              void* d_out, int out_size, void* d_ws, size_t ws_size,
                              hipStream_t stream) {
  const int*   idx   = (const int*)d_in[0];       // "input": int indices [N_IDX]
  const f32x4* table = (const f32x4*)d_in[1];     // "table": fp32 [N_EMB, 128]
  f32x4*       out   = (f32x4*)d_out;             // fp32 [N_IDX, 128]

  int n_idx = in_sizes[0];
  int total_threads = n_idx * 32;                 // 32 threads per row
  int block = 256;
  int grid = (total_threads + block - 1) / block;

  embed_gather_kernel<<<grid, block, 0, stream>>>(idx, table, out, n_idx);
}